// Round 18
// baseline (242.371 us; speedup 1.0000x reference)
//
#include <hip/hip_runtime.h>

#define NN 100000
#define NE 1600000
#define DIM 64
#define NPB 128            // nodes per bin
#define NBIN 782           // ceil(NN / NPB)
#define NBINP 1024         // padded for scans
#define ECHUNK 16384       // edges per chunk (~21-edge runs per (chunk,bin) segment)
#define NCHUNK ((NE + ECHUNK - 1) / ECHUNK)   // 98
#define NCHUNKP 128        // padded chunk count; k_hist MUST launch NCHUNKP blocks
                           // so tail chunks write zero counts (r16 lesson)

__device__ inline ushort f2bf(float f) {            // round-to-nearest-even
    unsigned u = __float_as_uint(f);
    unsigned r = u + 0x7FFFu + ((u >> 16) & 1u);
    return (ushort)(r >> 16);
}
__device__ inline float bfu(unsigned long long v, int k) {   // bf16 lane k of u64
    return __uint_as_float((unsigned)((v >> (k * 16)) & 0xFFFFu) << 16);
}

// Per-chunk histogram over bins (LDS atomics only). gcounts layout: [bin][chunk].
// Launched with NCHUNKP blocks: chunks >= NCHUNK write zeros (padding!).
__global__ __launch_bounds__(256) void k_hist(const int* __restrict__ dst,
                                              int* __restrict__ gcounts) {
    __shared__ int hist[NBINP];
    int tid = threadIdx.x, chunk = blockIdx.x;
    for (int j = tid; j < NBINP; j += 256) hist[j] = 0;
    __syncthreads();
    long long base = (long long)chunk * ECHUNK;
    long long lim = base + ECHUNK; if (lim > NE) lim = NE;
    for (long long i = base + tid; i < lim; i += 256)
        atomicAdd(&hist[dst[i] >> 7], 1);
    __syncthreads();
    for (int j = tid; j < NBINP; j += 256)
        gcounts[j * NCHUNKP + chunk] = hist[j];
}

// Per-bin exclusive scan over the (<=128) chunk axis, in place. 128 threads.
__global__ __launch_bounds__(128) void k_colscan(int* __restrict__ gcounts,
                                                 int* __restrict__ bintot) {
    __shared__ int sd[128];
    int t = threadIdx.x;
    int* p = gcounts + blockIdx.x * NCHUNKP;
    int v = p[t];
    sd[t] = v;
    __syncthreads();
    for (int off = 1; off < 128; off <<= 1) {
        int x = (t >= off) ? sd[t - off] : 0;
        __syncthreads();
        sd[t] += x;
        __syncthreads();
    }
    p[t] = sd[t] - v;                  // exclusive
    if (t == 127) bintot[blockIdx.x] = sd[127];
}

// Exclusive scan of 1024 bin totals -> binbase; also row_ptr[NN] = NE.
__global__ __launch_bounds__(256) void k_binscan(const int* __restrict__ bintot,
                                                 int* __restrict__ binbase,
                                                 int* __restrict__ row_ptr) {
    __shared__ int sd[256];
    int t = threadIdx.x;
    int v[4], s = 0;
    #pragma unroll
    for (int i = 0; i < 4; i++) { v[i] = bintot[t * 4 + i]; s += v[i]; }
    sd[t] = s;
    __syncthreads();
    for (int off = 1; off < 256; off <<= 1) {
        int x = (t >= off) ? sd[t - off] : 0;
        __syncthreads();
        sd[t] += x;
        __syncthreads();
    }
    int excl = sd[t] - s;
    #pragma unroll
    for (int i = 0; i < 4; i++) { binbase[t * 4 + i] = excl; excl += v[i]; }
    if (t == 255) { binbase[NBINP] = sd[255]; row_ptr[NN] = sd[255]; }
}

// Stable scatter of edges into their bin's contiguous range. No global atomics.
// meta = src (17b) | dst_local (7b) << 17
__global__ __launch_bounds__(256) void k_scatbin(const int* __restrict__ src,
                                                 const int* __restrict__ dst,
                                                 const float* __restrict__ w,
                                                 const int* __restrict__ gcounts,
                                                 const int* __restrict__ binbase,
                                                 int2* __restrict__ binned) {
    __shared__ int lcur[NBINP];
    int tid = threadIdx.x, chunk = blockIdx.x;
    for (int j = tid; j < NBINP; j += 256) lcur[j] = 0;
    __syncthreads();
    long long base = (long long)chunk * ECHUNK;
    long long lim = base + ECHUNK; if (lim > NE) lim = NE;
    for (long long i = base + tid; i < lim; i += 256) {
        int d = dst[i];
        int b = d >> 7;
        int r = atomicAdd(&lcur[b], 1);                       // LDS atomic
        int pos = binbase[b] + gcounts[b * NCHUNKP + chunk] + r;
        int meta = src[i] | ((d & 127) << 17);
        binned[pos] = make_int2(meta, __float_as_int(w[i]));
    }
}

// Per-bin: per-node grouping + row_ptr + dinv + PACKED edata (src<<15 | q15(w))
// + bf16 pre-scaled table conversion for this bin's 128 x-rows.
__global__ __launch_bounds__(256) void k_group(const int2* __restrict__ binned,
                                               const int* __restrict__ binbase,
                                               const float* __restrict__ x,
                                               unsigned* __restrict__ edata,
                                               int* __restrict__ row_ptr,
                                               float* __restrict__ dinv,
                                               ushort* __restrict__ Hb0) {
    __shared__ int ndeg[NPB];
    __shared__ float nws[NPB];     // weight sums, then dinv values
    __shared__ int ncur[NPB];
    __shared__ int sd[NPB];
    int t = threadIdx.x, bin = blockIdx.x;
    int beg = binbase[bin], end = binbase[bin + 1];
    if (t < NPB) { ndeg[t] = 0; nws[t] = 0.f; }
    __syncthreads();
    for (int e = beg + t; e < end; e += 256) {
        int2 v = binned[e];
        int dl = ((unsigned)v.x) >> 17;
        atomicAdd(&ndeg[dl], 1);
        atomicAdd(&nws[dl], __int_as_float(v.y));
    }
    __syncthreads();
    int own = 0;
    if (t < NPB) { own = ndeg[t]; sd[t] = own; }
    __syncthreads();
    for (int off = 1; off < NPB; off <<= 1) {
        int xx = (t >= off && t < NPB) ? sd[t - off] : 0;
        __syncthreads();
        if (t < NPB) sd[t] += xx;
        __syncthreads();
    }
    if (t < NPB) {
        int excl = sd[t] - own;
        ncur[t] = excl;
        float dv = rsqrtf(1.0f + nws[t]);
        nws[t] = dv;                       // nws now holds dinv
        int node = bin * NPB + t;
        if (node < NN) {
            row_ptr[node] = beg + excl;
            dinv[node] = dv;
        }
    }
    __syncthreads();
    // scatter to packed per-node edata
    for (int e = beg + t; e < end; e += 256) {
        int2 v = binned[e];
        int dl = ((unsigned)v.x) >> 17;
        int r = atomicAdd(&ncur[dl], 1);
        unsigned q15 = __float2uint_rn(__int_as_float(v.y) * 32767.0f);
        edata[beg + r] = ((unsigned)(v.x & 0x1FFFF) << 15) | q15;
    }
    // bf16 pre-scaled table for this bin's rows: Hb0[node] = dinv[node]*x[node]
    int rowlim = min(NPB, NN - bin * NPB);
    for (int idx = t; idx < rowlim * 16; idx += 256) {    // 16 float4 per row
        int row = idx >> 4;
        int node = bin * NPB + row;
        float dn = nws[row];
        float4 v = reinterpret_cast<const float4*>(x)[(size_t)node * 16 + (idx & 15)];
        ushort4 o;
        o.x = f2bf(v.x * dn); o.y = f2bf(v.y * dn);
        o.z = f2bf(v.z * dn); o.w = f2bf(v.w * dn);
        reinterpret_cast<ushort4*>(Hb0)[(size_t)node * 16 + (idx & 15)] = o;
    }
}

#define FMA4U(acc, nm, q) \
    acc.x = fmaf(nm, bfu(q, 0), acc.x); acc.y = fmaf(nm, bfu(q, 1), acc.y); \
    acc.z = fmaf(nm, bfu(q, 2), acc.z); acc.w = fmaf(nm, bfu(q, 3), acc.w);

// Plain (cached) 8B bf16x4 row-slice gather — L1/L2 retention helps (r12 lesson).
#define LDROW(idx) (*reinterpret_cast<const unsigned long long*>( \
    Hb + ((size_t)(idx) << 6) + (l << 2)))
#define DEQ(v) ((float)((v) & 0x7FFFu) * (1.0f / 32767.0f))

// Fused layer. ONE NODE PER 16-LANE GROUP (4 consecutive nodes per wave).
// Table Hb is PRE-SCALED: t[s] = dinv[s]*A[s]. edata = (src<<15)|q15(w).
// Epilogue: W column in 64 VGPRs; rowbuf via uniform-address float4 broadcasts.
template <int RELU>
__global__ __launch_bounds__(256, 4) void k_layer(const int* __restrict__ row_ptr,
                                                  const unsigned* __restrict__ edata,
                                                  const ushort* __restrict__ Hb,
                                                  const float* __restrict__ W,
                                                  const float* __restrict__ bias,
                                                  const float* __restrict__ dinv,
                                                  ushort* __restrict__ OutB,
                                                  float* __restrict__ OutF, int n) {
    __shared__ float rowbuf[4][4][68];   // [wave][group/node][ch pad 68] 4.3 KB
    int tid = threadIdx.x;
    int lane = tid & 63, wv = tid >> 6;
    int g = lane >> 4, l = lane & 15;

    // my output column of W in registers (64 coalesced loads, static indexing)
    float wr[64];
    #pragma unroll
    for (int k = 0; k < 64; k++) wr[k] = W[k * 64 + lane];
    float bl = bias[lane];

    int wave_id = blockIdx.x * 4 + wv;
    int nwaves = gridDim.x * 4;

    for (int base = wave_id * 4; base < n; base += nwaves * 4) {
        int node = base + g;
        bool valid = node < n;
        int beg = 0, end = 0;
        float dn = 0.f;
        if (valid) { beg = row_ptr[node]; end = row_ptr[node + 1]; dn = dinv[node]; }
        // self-row (pre-scaled) issued early
        unsigned long long svq = LDROW(valid ? node : 0);

        float4 acc = make_float4(0.f, 0.f, 0.f, 0.f);
        int e = beg;
        for (; e + 7 < end; e += 8) {          // 8 gathers in flight per group
            unsigned ev[8];
            unsigned long long q[8];
            #pragma unroll
            for (int u = 0; u < 8; u++) ev[u] = edata[e + u];
            #pragma unroll
            for (int u = 0; u < 8; u++) q[u] = LDROW(ev[u] >> 15);
            #pragma unroll
            for (int u = 0; u < 8; u++) {
                float nm = DEQ(ev[u]);
                FMA4U(acc, nm, q[u]);
            }
        }
        if (e + 3 < end) {
            unsigned ev[4];
            unsigned long long q[4];
            #pragma unroll
            for (int u = 0; u < 4; u++) ev[u] = edata[e + u];
            #pragma unroll
            for (int u = 0; u < 4; u++) q[u] = LDROW(ev[u] >> 15);
            #pragma unroll
            for (int u = 0; u < 4; u++) {
                float nm = DEQ(ev[u]);
                FMA4U(acc, nm, q[u]);
            }
            e += 4;
        }
        if (e + 1 < end) {
            unsigned e0 = edata[e], e1 = edata[e + 1];
            unsigned long long q0 = LDROW(e0 >> 15), q1 = LDROW(e1 >> 15);
            FMA4U(acc, DEQ(e0), q0); FMA4U(acc, DEQ(e1), q1);
            e += 2;
        }
        if (e < end) {
            unsigned e0 = edata[e];
            unsigned long long q0 = LDROW(e0 >> 15);
            FMA4U(acc, DEQ(e0), q0);
        }

        // self-loop (table pre-scaled: add t[self], then scale whole row by dn)
        acc.x = (acc.x + bfu(svq, 0)) * dn;
        acc.y = (acc.y + bfu(svq, 1)) * dn;
        acc.z = (acc.z + bfu(svq, 2)) * dn;
        acc.w = (acc.w + bfu(svq, 3)) * dn;
        *reinterpret_cast<float4*>(&rowbuf[wv][g][l * 4]) = acc;
        __builtin_amdgcn_wave_barrier();

        // epilogue: 4 nodes; rowbuf via float4 broadcast, W from registers
        #pragma unroll 1
        for (int j = 0; j < 4; j++) {
            int onode = base + j;
            if (onode >= n) break;
            float o = 0.f;
            #pragma unroll
            for (int k4 = 0; k4 < 16; k4++) {
                float4 r = *reinterpret_cast<const float4*>(&rowbuf[wv][j][k4 * 4]);
                o = fmaf(r.x, wr[k4 * 4 + 0], o);
                o = fmaf(r.y, wr[k4 * 4 + 1], o);
                o = fmaf(r.z, wr[k4 * 4 + 2], o);
                o = fmaf(r.w, wr[k4 * 4 + 3], o);
            }
            o += bl;
            if (RELU) {
                o = fmaxf(o, 0.f);
                OutB[(size_t)onode * DIM + lane] = f2bf(o * dinv[onode]);
            } else {
                OutF[(size_t)onode * DIM + lane] = o;
            }
        }
        __builtin_amdgcn_wave_barrier();
    }
}

extern "C" void kernel_launch(void* const* d_in, const int* in_sizes, int n_in,
                              void* d_out, int out_size, void* d_ws, size_t ws_size,
                              hipStream_t stream) {
    const float* x  = (const float*)d_in[0];
    const int* ei   = (const int*)d_in[1];   // [2][NE] int32
    const float* ew = (const float*)d_in[2];
    const float* W1 = (const float*)d_in[3];
    const float* b1 = (const float*)d_in[4];
    const float* W2 = (const float*)d_in[5];
    const float* b2 = (const float*)d_in[6];
    const float* W3 = (const float*)d_in[7];
    const float* b3 = (const float*)d_in[8];
    float* out = (float*)d_out;

    const int* src = ei;
    const int* dst = ei + NE;

    auto align = [](size_t v) { return (v + 255) / 256 * 256; };
    char* ws = (char*)d_ws;
    // persistent:
    int*      row_ptr = (int*)ws;      ws += align(((size_t)NN + 1) * 4);
    float*    dinv    = (float*)ws;    ws += align((size_t)NN * 4);
    unsigned* edata   = (unsigned*)ws; ws += align((size_t)NE * 4);        // 6.4 MB
    ushort*   Hb0     = (ushort*)ws;   ws += align((size_t)NN * DIM * 2);  // 12.8 MB
    ushort*   A1b     = (ushort*)ws;   ws += align((size_t)NN * DIM * 2);  // 12.8 MB
    ushort*   A2b     = (ushort*)ws;   ws += align((size_t)NN * DIM * 2);  // 12.8 MB
    // build temporaries:
    int*  gcounts = (int*)ws;  ws += align((size_t)NBINP * NCHUNKP * 4);   // 0.5 MB
    int*  bintot  = (int*)ws;  ws += align((size_t)NBINP * 4);
    int*  binbase = (int*)ws;  ws += align(((size_t)NBINP + 1) * 4);
    int2* binned  = (int2*)ws;                                             // 12.8 MB

    const int gL = 2048;

    // ---- deterministic CSR build: zero global atomics ----
    // NCHUNKP blocks (not NCHUNK): tail chunks must write zero counts.
    k_hist<<<NCHUNKP, 256, 0, stream>>>(dst, gcounts);
    k_colscan<<<NBINP, 128, 0, stream>>>(gcounts, bintot);
    k_binscan<<<1, 256, 0, stream>>>(bintot, binbase, row_ptr);
    k_scatbin<<<NCHUNK, 256, 0, stream>>>(src, dst, ew, gcounts, binbase, binned);
    k_group<<<NBIN, 256, 0, stream>>>(binned, binbase, x, edata, row_ptr, dinv, Hb0);

    // ---- fused layers: pre-scaled bf16 tables, packed edges, fp32 math ----
    k_layer<1><<<gL, 256, 0, stream>>>(row_ptr, edata, Hb0, W1, b1, dinv, A1b, nullptr, NN);
    k_layer<1><<<gL, 256, 0, stream>>>(row_ptr, edata, A1b, W2, b2, dinv, A2b, nullptr, NN);
    k_layer<0><<<gL, 256, 0, stream>>>(row_ptr, edata, A2b, W3, b3, dinv, nullptr, out, NN);
}

// Round 19
// 207.769 us; speedup vs baseline: 1.1665x; 1.1665x over previous
//
#include <hip/hip_runtime.h>

#define NN 100000
#define NE 1600000
#define DIM 64
#define NPB 128            // nodes per bin
#define NBIN 782           // ceil(NN / NPB)
#define NBINP 1024         // padded for scans
#define ECHUNK 8192        // edges per chunk (196 chunks: parallelism x run-length optimum, r18 lesson)
#define NCHUNK ((NE + ECHUNK - 1) / ECHUNK)   // 196
#define NCHUNKP 256        // padded chunk count; k_hist MUST launch NCHUNKP blocks
                           // so tail chunks write zero counts (r16 lesson)

__device__ inline ushort f2bf(float f) {            // round-to-nearest-even
    unsigned u = __float_as_uint(f);
    unsigned r = u + 0x7FFFu + ((u >> 16) & 1u);
    return (ushort)(r >> 16);
}
__device__ inline float bfu(unsigned long long v, int k) {   // bf16 lane k of u64
    return __uint_as_float((unsigned)((v >> (k * 16)) & 0xFFFFu) << 16);
}

// Per-chunk histogram over bins (LDS atomics only). gcounts layout: [bin][chunk].
// Launched with NCHUNKP blocks x 512 threads: chunks >= NCHUNK write zeros.
__global__ __launch_bounds__(512) void k_hist(const int* __restrict__ dst,
                                              int* __restrict__ gcounts) {
    __shared__ int hist[NBINP];
    int tid = threadIdx.x, chunk = blockIdx.x;
    for (int j = tid; j < NBINP; j += 512) hist[j] = 0;
    __syncthreads();
    int base = chunk * ECHUNK;
    int lim = min(base + ECHUNK, NE);
    for (int i = base + tid; i < lim; i += 512)
        atomicAdd(&hist[dst[i] >> 7], 1);
    __syncthreads();
    for (int j = tid; j < NBINP; j += 512)
        gcounts[j * NCHUNKP + chunk] = hist[j];
}

// Per-bin exclusive scan over the (<=256) chunk axis, in place.
__global__ __launch_bounds__(256) void k_colscan(int* __restrict__ gcounts,
                                                 int* __restrict__ bintot) {
    __shared__ int sd[256];
    int t = threadIdx.x;
    int* p = gcounts + blockIdx.x * NCHUNKP;
    int v = p[t];
    sd[t] = v;
    __syncthreads();
    for (int off = 1; off < 256; off <<= 1) {
        int x = (t >= off) ? sd[t - off] : 0;
        __syncthreads();
        sd[t] += x;
        __syncthreads();
    }
    p[t] = sd[t] - v;                  // exclusive
    if (t == 255) bintot[blockIdx.x] = sd[255];
}

// Exclusive scan of 1024 bin totals -> binbase; also row_ptr[NN] = NE.
__global__ __launch_bounds__(256) void k_binscan(const int* __restrict__ bintot,
                                                 int* __restrict__ binbase,
                                                 int* __restrict__ row_ptr) {
    __shared__ int sd[256];
    int t = threadIdx.x;
    int v[4], s = 0;
    #pragma unroll
    for (int i = 0; i < 4; i++) { v[i] = bintot[t * 4 + i]; s += v[i]; }
    sd[t] = s;
    __syncthreads();
    for (int off = 1; off < 256; off <<= 1) {
        int x = (t >= off) ? sd[t - off] : 0;
        __syncthreads();
        sd[t] += x;
        __syncthreads();
    }
    int excl = sd[t] - s;
    #pragma unroll
    for (int i = 0; i < 4; i++) { binbase[t * 4 + i] = excl; excl += v[i]; }
    if (t == 255) { binbase[NBINP] = sd[255]; row_ptr[NN] = sd[255]; }
}

// Stable scatter of edges into their bin's contiguous range. No global atomics.
// 512 threads/block: 2x loads/stores in flight per (low-count) chunk block.
// meta = src (17b) | dst_local (7b) << 17
__global__ __launch_bounds__(512) void k_scatbin(const int* __restrict__ src,
                                                 const int* __restrict__ dst,
                                                 const float* __restrict__ w,
                                                 const int* __restrict__ gcounts,
                                                 const int* __restrict__ binbase,
                                                 int2* __restrict__ binned) {
    __shared__ int lcur[NBINP];
    int tid = threadIdx.x, chunk = blockIdx.x;
    for (int j = tid; j < NBINP; j += 512) lcur[j] = 0;
    __syncthreads();
    int base = chunk * ECHUNK;
    int lim = min(base + ECHUNK, NE);
    for (int i = base + tid; i < lim; i += 512) {
        int d = dst[i];
        int b = d >> 7;
        int r = atomicAdd(&lcur[b], 1);                       // LDS atomic
        int pos = binbase[b] + gcounts[b * NCHUNKP + chunk] + r;
        int meta = src[i] | ((d & 127) << 17);
        binned[pos] = make_int2(meta, __float_as_int(w[i]));
    }
}

// Per-bin: per-node grouping + row_ptr + dinv + PACKED edata (src<<15 | q15(w))
// + bf16 pre-scaled table conversion for this bin's 128 x-rows.
__global__ __launch_bounds__(256) void k_group(const int2* __restrict__ binned,
                                               const int* __restrict__ binbase,
                                               const float* __restrict__ x,
                                               unsigned* __restrict__ edata,
                                               int* __restrict__ row_ptr,
                                               float* __restrict__ dinv,
                                               ushort* __restrict__ Hb0) {
    __shared__ int ndeg[NPB];
    __shared__ float nws[NPB];     // weight sums, then dinv values
    __shared__ int ncur[NPB];
    __shared__ int sd[NPB];
    int t = threadIdx.x, bin = blockIdx.x;
    int beg = binbase[bin], end = binbase[bin + 1];
    if (t < NPB) { ndeg[t] = 0; nws[t] = 0.f; }
    __syncthreads();
    for (int e = beg + t; e < end; e += 256) {
        int2 v = binned[e];
        int dl = ((unsigned)v.x) >> 17;
        atomicAdd(&ndeg[dl], 1);
        atomicAdd(&nws[dl], __int_as_float(v.y));
    }
    __syncthreads();
    int own = 0;
    if (t < NPB) { own = ndeg[t]; sd[t] = own; }
    __syncthreads();
    for (int off = 1; off < NPB; off <<= 1) {
        int xx = (t >= off && t < NPB) ? sd[t - off] : 0;
        __syncthreads();
        if (t < NPB) sd[t] += xx;
        __syncthreads();
    }
    if (t < NPB) {
        int excl = sd[t] - own;
        ncur[t] = excl;
        float dv = rsqrtf(1.0f + nws[t]);
        nws[t] = dv;                       // nws now holds dinv
        int node = bin * NPB + t;
        if (node < NN) {
            row_ptr[node] = beg + excl;
            dinv[node] = dv;
        }
    }
    __syncthreads();
    // scatter to packed per-node edata
    for (int e = beg + t; e < end; e += 256) {
        int2 v = binned[e];
        int dl = ((unsigned)v.x) >> 17;
        int r = atomicAdd(&ncur[dl], 1);
        unsigned q15 = __float2uint_rn(__int_as_float(v.y) * 32767.0f);
        edata[beg + r] = ((unsigned)(v.x & 0x1FFFF) << 15) | q15;
    }
    // bf16 pre-scaled table for this bin's rows: Hb0[node] = dinv[node]*x[node]
    int rowlim = min(NPB, NN - bin * NPB);
    for (int idx = t; idx < rowlim * 16; idx += 256) {    // 16 float4 per row
        int row = idx >> 4;
        int node = bin * NPB + row;
        float dn = nws[row];
        float4 v = reinterpret_cast<const float4*>(x)[(size_t)node * 16 + (idx & 15)];
        ushort4 o;
        o.x = f2bf(v.x * dn); o.y = f2bf(v.y * dn);
        o.z = f2bf(v.z * dn); o.w = f2bf(v.w * dn);
        reinterpret_cast<ushort4*>(Hb0)[(size_t)node * 16 + (idx & 15)] = o;
    }
}

#define FMA4U(acc, nm, q) \
    acc.x = fmaf(nm, bfu(q, 0), acc.x); acc.y = fmaf(nm, bfu(q, 1), acc.y); \
    acc.z = fmaf(nm, bfu(q, 2), acc.z); acc.w = fmaf(nm, bfu(q, 3), acc.w);

// Plain (cached) 8B bf16x4 row-slice gather — L1/L2 retention helps (r12 lesson).
#define LDROW(idx) (*reinterpret_cast<const unsigned long long*>( \
    Hb + ((size_t)(idx) << 6) + (l << 2)))
#define DEQ(v) ((float)((v) & 0x7FFFu) * (1.0f / 32767.0f))

// Fused layer. ONE NODE PER 16-LANE GROUP (4 consecutive nodes per wave).
// Table Hb is PRE-SCALED: t[s] = dinv[s]*A[s]. edata = (src<<15)|q15(w).
// Epilogue: W column in 64 VGPRs; rowbuf via uniform-address float4 broadcasts.
template <int RELU>
__global__ __launch_bounds__(256, 4) void k_layer(const int* __restrict__ row_ptr,
                                                  const unsigned* __restrict__ edata,
                                                  const ushort* __restrict__ Hb,
                                                  const float* __restrict__ W,
                                                  const float* __restrict__ bias,
                                                  const float* __restrict__ dinv,
                                                  ushort* __restrict__ OutB,
                                                  float* __restrict__ OutF, int n) {
    __shared__ float rowbuf[4][4][68];   // [wave][group/node][ch pad 68] 4.3 KB
    int tid = threadIdx.x;
    int lane = tid & 63, wv = tid >> 6;
    int g = lane >> 4, l = lane & 15;

    // my output column of W in registers (64 coalesced loads, static indexing)
    float wr[64];
    #pragma unroll
    for (int k = 0; k < 64; k++) wr[k] = W[k * 64 + lane];
    float bl = bias[lane];

    int wave_id = blockIdx.x * 4 + wv;
    int nwaves = gridDim.x * 4;

    for (int base = wave_id * 4; base < n; base += nwaves * 4) {
        int node = base + g;
        bool valid = node < n;
        int beg = 0, end = 0;
        float dn = 0.f;
        if (valid) { beg = row_ptr[node]; end = row_ptr[node + 1]; dn = dinv[node]; }
        // self-row (pre-scaled) issued early
        unsigned long long svq = LDROW(valid ? node : 0);

        float4 acc = make_float4(0.f, 0.f, 0.f, 0.f);
        int e = beg;
        for (; e + 7 < end; e += 8) {          // 8 gathers in flight per group
            unsigned ev[8];
            unsigned long long q[8];
            #pragma unroll
            for (int u = 0; u < 8; u++) ev[u] = edata[e + u];
            #pragma unroll
            for (int u = 0; u < 8; u++) q[u] = LDROW(ev[u] >> 15);
            #pragma unroll
            for (int u = 0; u < 8; u++) {
                float nm = DEQ(ev[u]);
                FMA4U(acc, nm, q[u]);
            }
        }
        if (e + 3 < end) {
            unsigned ev[4];
            unsigned long long q[4];
            #pragma unroll
            for (int u = 0; u < 4; u++) ev[u] = edata[e + u];
            #pragma unroll
            for (int u = 0; u < 4; u++) q[u] = LDROW(ev[u] >> 15);
            #pragma unroll
            for (int u = 0; u < 4; u++) {
                float nm = DEQ(ev[u]);
                FMA4U(acc, nm, q[u]);
            }
            e += 4;
        }
        if (e + 1 < end) {
            unsigned e0 = edata[e], e1 = edata[e + 1];
            unsigned long long q0 = LDROW(e0 >> 15), q1 = LDROW(e1 >> 15);
            FMA4U(acc, DEQ(e0), q0); FMA4U(acc, DEQ(e1), q1);
            e += 2;
        }
        if (e < end) {
            unsigned e0 = edata[e];
            unsigned long long q0 = LDROW(e0 >> 15);
            FMA4U(acc, DEQ(e0), q0);
        }

        // self-loop (table pre-scaled: add t[self], then scale whole row by dn)
        acc.x = (acc.x + bfu(svq, 0)) * dn;
        acc.y = (acc.y + bfu(svq, 1)) * dn;
        acc.z = (acc.z + bfu(svq, 2)) * dn;
        acc.w = (acc.w + bfu(svq, 3)) * dn;
        *reinterpret_cast<float4*>(&rowbuf[wv][g][l * 4]) = acc;
        __builtin_amdgcn_wave_barrier();

        // epilogue: 4 nodes; rowbuf via float4 broadcast, W from registers
        #pragma unroll 1
        for (int j = 0; j < 4; j++) {
            int onode = base + j;
            if (onode >= n) break;
            float o = 0.f;
            #pragma unroll
            for (int k4 = 0; k4 < 16; k4++) {
                float4 r = *reinterpret_cast<const float4*>(&rowbuf[wv][j][k4 * 4]);
                o = fmaf(r.x, wr[k4 * 4 + 0], o);
                o = fmaf(r.y, wr[k4 * 4 + 1], o);
                o = fmaf(r.z, wr[k4 * 4 + 2], o);
                o = fmaf(r.w, wr[k4 * 4 + 3], o);
            }
            o += bl;
            if (RELU) {
                o = fmaxf(o, 0.f);
                OutB[(size_t)onode * DIM + lane] = f2bf(o * dinv[onode]);
            } else {
                OutF[(size_t)onode * DIM + lane] = o;
            }
        }
        __builtin_amdgcn_wave_barrier();
    }
}

extern "C" void kernel_launch(void* const* d_in, const int* in_sizes, int n_in,
                              void* d_out, int out_size, void* d_ws, size_t ws_size,
                              hipStream_t stream) {
    const float* x  = (const float*)d_in[0];
    const int* ei   = (const int*)d_in[1];   // [2][NE] int32
    const float* ew = (const float*)d_in[2];
    const float* W1 = (const float*)d_in[3];
    const float* b1 = (const float*)d_in[4];
    const float* W2 = (const float*)d_in[5];
    const float* b2 = (const float*)d_in[6];
    const float* W3 = (const float*)d_in[7];
    const float* b3 = (const float*)d_in[8];
    float* out = (float*)d_out;

    const int* src = ei;
    const int* dst = ei + NE;

    auto align = [](size_t v) { return (v + 255) / 256 * 256; };
    char* ws = (char*)d_ws;
    // persistent:
    int*      row_ptr = (int*)ws;      ws += align(((size_t)NN + 1) * 4);
    float*    dinv    = (float*)ws;    ws += align((size_t)NN * 4);
    unsigned* edata   = (unsigned*)ws; ws += align((size_t)NE * 4);        // 6.4 MB
    ushort*   Hb0     = (ushort*)ws;   ws += align((size_t)NN * DIM * 2);  // 12.8 MB
    ushort*   A1b     = (ushort*)ws;   ws += align((size_t)NN * DIM * 2);  // 12.8 MB
    ushort*   A2b     = (ushort*)ws;   ws += align((size_t)NN * DIM * 2);  // 12.8 MB
    // build temporaries:
    int*  gcounts = (int*)ws;  ws += align((size_t)NBINP * NCHUNKP * 4);   // 1 MB
    int*  bintot  = (int*)ws;  ws += align((size_t)NBINP * 4);
    int*  binbase = (int*)ws;  ws += align(((size_t)NBINP + 1) * 4);
    int2* binned  = (int2*)ws;                                             // 12.8 MB

    const int gL = 2048;

    // ---- deterministic CSR build: zero global atomics ----
    // NCHUNKP blocks (not NCHUNK): tail chunks must write zero counts.
    k_hist<<<NCHUNKP, 512, 0, stream>>>(dst, gcounts);
    k_colscan<<<NBINP, 256, 0, stream>>>(gcounts, bintot);
    k_binscan<<<1, 256, 0, stream>>>(bintot, binbase, row_ptr);
    k_scatbin<<<NCHUNK, 512, 0, stream>>>(src, dst, ew, gcounts, binbase, binned);
    k_group<<<NBIN, 256, 0, stream>>>(binned, binbase, x, edata, row_ptr, dinv, Hb0);

    // ---- fused layers: pre-scaled bf16 tables, packed edges, fp32 math ----
    k_layer<1><<<gL, 256, 0, stream>>>(row_ptr, edata, Hb0, W1, b1, dinv, A1b, nullptr, NN);
    k_layer<1><<<gL, 256, 0, stream>>>(row_ptr, edata, A1b, W2, b2, dinv, A2b, nullptr, NN);
    k_layer<0><<<gL, 256, 0, stream>>>(row_ptr, edata, A2b, W3, b3, dinv, nullptr, out, NN);
}